// Round 5
// baseline (332.447 us; speedup 1.0000x reference)
//
#include <hip/hip_runtime.h>
#include <math.h>

#define NDIN 128
#define NHID 128
#define NDOUT 64

typedef _Float16 half2_t __attribute__((ext_vector_type(2)));
typedef _Float16 half4_t __attribute__((ext_vector_type(4)));
typedef _Float16 half8_t __attribute__((ext_vector_type(8)));
typedef float    float4v __attribute__((ext_vector_type(4)));

__device__ __forceinline__ float gelu_exact(float x) {
    return 0.5f * x * (1.0f + erff(x * 0.70710678118654752f));
}

// ---------------- prep0: 3x weight transpose+cast, zero count & done ----------------
// W[K][N] fp32 -> Wt[N][K] fp16, 32x32 LDS tiles.

__device__ void wtrans_tile(const float* __restrict__ W, _Float16* __restrict__ Wt,
                            int K, int N, int bx, int by) {
    __shared__ float tile[32][33];
    int tx = threadIdx.x & 31, ty = threadIdx.x >> 5;   // ty 0..7
    for (int i = 0; i < 32; i += 8) {
        int k = by * 32 + ty + i, nn = bx * 32 + tx;
        tile[ty + i][tx] = (k < K && nn < N) ? W[(size_t)k * N + nn] : 0.f;
    }
    __syncthreads();
    for (int i = 0; i < 32; i += 8) {
        int nn = bx * 32 + ty + i, k = by * 32 + tx;
        if (nn < N && k < K) Wt[(size_t)nn * K + k] = (_Float16)tile[tx][ty + i];
    }
}

// blocks: [0,16) W1; [16,32) W2; [32,40) W3; [40,40+NB) zero count (+done in block 40)
__global__ __launch_bounds__(256) void prep0_kernel(
    const float* __restrict__ W1, _Float16* __restrict__ W1t,
    const float* __restrict__ W2, _Float16* __restrict__ W2t,
    const float* __restrict__ W3, _Float16* __restrict__ W3t,
    int* __restrict__ count, int* __restrict__ done, int n) {
    int b = blockIdx.x;
    if (b < 16) {
        wtrans_tile(W1, W1t, NDIN, NHID, b & 3, b >> 2);
    } else if (b < 32) {
        wtrans_tile(W2, W2t, NHID, NHID, (b - 16) & 3, (b - 16) >> 2);
    } else if (b < 40) {
        wtrans_tile(W3, W3t, NHID, NDOUT, (b - 32) & 1, (b - 32) >> 1);
    } else {
        int z = b - 40;
        int i = z * 256 + threadIdx.x;
        if (i < n) count[i] = 0;
        if (z == 0 && threadIdx.x < 64) done[threadIdx.x] = 0;  // done[0..2] sync slots
    }
}

// ---------------- shared GEMM phase: T[64,BN] tile = lds_a[64,128] @ Bt^T --------------
// B operand straight from global: 32 KB fp16 weight is L1/L2-resident after first touch.
// Only 17.4 KB LDS -> work fused in the same kernel keeps 8-block/CU occupancy
// (avoids the 52 KB lds_bt trap that caused the R5-era regression).

template <int BN>
__device__ __forceinline__ void gemm_phaseB(
    const _Float16 (*lds_a)[136], const _Float16* __restrict__ Bt,
    _Float16* __restrict__ T, int bm, int M) {
    int tid = threadIdx.x;
    int wave = tid >> 6, lane = tid & 63;
    int m = lane & 15, quad = lane >> 4;
    const int NT = BN / 16;
    float4v acc[NT];
#pragma unroll
    for (int nt = 0; nt < NT; nt++) acc[nt] = (float4v){0.f, 0.f, 0.f, 0.f};
    int arow = (wave << 4) + m;
#pragma unroll
    for (int kc = 0; kc < 128; kc += 32) {
        half8_t a = *(const half8_t*)&lds_a[arow][kc + quad * 8];
#pragma unroll
        for (int nt = 0; nt < NT; nt++) {
            half8_t b = *(const half8_t*)&Bt[(size_t)(nt * 16 + m) * 128 + kc + quad * 8];
            acc[nt] = __builtin_amdgcn_mfma_f32_16x16x32_f16(a, b, acc[nt], 0, 0, 0);
        }
    }
#pragma unroll
    for (int nt = 0; nt < NT; nt++) {
#pragma unroll
        for (int r = 0; r < 4; r++) {
            int grow = bm + (wave << 4) + (quad << 2) + r;
            if (grow < M) T[(size_t)grow * BN + nt * 16 + m] = (_Float16)acc[nt][r];
        }
    }
}

// ---------------- count+slot (blocks [0,cblocks)) || gemm1 (rest) ----------------
// Both depend ONLY on prep0 (zeroed count / W1t) -> independent, one launch.
// count blocks: one atomicAdd each, drain fast; gemm blocks follow immediately.
// (R1's fill+gemm fusion failed because fill itself was 46 us of latency-bound
// scatter; count is ~one-atomic-per-thread and retires in waves.)

__global__ __launch_bounds__(256) void count_gemm1_kernel(
    const int* __restrict__ dst, int* __restrict__ count, int* __restrict__ eslot, int E,
    const float* __restrict__ x, const _Float16* __restrict__ W1t,
    _Float16* __restrict__ T, int M, int cblocks) {
    __shared__ _Float16 lds_a[64][136];
    int b = blockIdx.x;
    if (b < cblocks) {                          // ---- degree count + slot assignment ----
        int e = b * 256 + threadIdx.x;
        if (e < E) eslot[e] = atomicAdd(&count[dst[e]], 1);
        return;
    }
    // ---- gemm1: stage x (fp32 -> fp16) then MFMA (global-B, 17.4 KB LDS) ----
    int bm = (b - cblocks) * 64;
    int tid = threadIdx.x;
#pragma unroll
    for (int j = 0; j < 8; j++) {
        int c = tid + j * 256;
        int r = c >> 5, col = (c & 31) << 2;
        int grow = bm + r;
        float4 v = make_float4(0.f, 0.f, 0.f, 0.f);
        if (grow < M) v = *(const float4*)(x + (size_t)grow * 128 + col);
        half4_t h;
        h[0] = (_Float16)v.x; h[1] = (_Float16)v.y;
        h[2] = (_Float16)v.z; h[3] = (_Float16)v.w;
        *(half4_t*)&lds_a[r][col] = h;
    }
    __syncthreads();
    gemm_phaseB<128>(lds_a, W1t, T, bm, M);
}

// ---------------- merged scan + dinv + CSR fill ----------------
// Phase 1 (threads 0..255 of each of nb blocks): block reduce -> last-arriving block
// scans partials (done[0] ctr, done[1] flag) -> per-block scan -> rowptr/dinv.
// Phase 2: arrive-counter done[2]; all nb blocks spin until ==nb. Deadlock-free:
// 196 blocks of 1024 thr = <=2/CU -> all co-resident on 256 CUs, and every block
// arrives BEFORE spinning, so the counter always reaches nb.
// Phase 3: grid-stride fill. Cross-XCD coherence: rowptr (written THIS kernel by other
// blocks) is read via device-scope atomic loads; edge weights recomputed from count[]
// (stable since the previous launch -> plain loads safe). adj consumed next launch.

__global__ __launch_bounds__(1024) void scan_fill_kernel(
    const int* __restrict__ count, int* __restrict__ blocksum, int* __restrict__ blockoff,
    int* __restrict__ rowptr, float* __restrict__ dinv, int* __restrict__ done,
    const int* __restrict__ src, const int* __restrict__ dst,
    const int* __restrict__ eslot, int2* __restrict__ adj,
    int nb, int n, int E) {
    __shared__ int s[256];
    __shared__ int flag;
    __shared__ int boff_s;
    int t = threadIdx.x;
    bool sc = t < 256;
    int i = blockIdx.x * 256 + t;          // meaningful only when sc
    int v = 0;
    if (sc) { v = (i < n) ? count[i] : 0; s[t] = v; }
    __syncthreads();
    for (int off = 128; off > 0; off >>= 1) {
        if (sc && t < off) s[t] += s[t + off];
        __syncthreads();
    }
    if (t == 0) {
        atomicExch(&blocksum[blockIdx.x], s[0]);
        __threadfence();
        int old = atomicAdd(&done[0], 1);
        flag = (old == nb - 1) ? 1 : 0;
    }
    __syncthreads();
    if (flag) {  // last block: scan the per-block partials, publish offsets + flag
        __threadfence();
        int pv = 0;
        if (sc) { pv = (t < nb) ? atomicAdd(&blocksum[t], 0) : 0; s[t] = pv; }
        __syncthreads();
        for (int off = 1; off < 256; off <<= 1) {
            int u = (sc && t >= off) ? s[t - off] : 0;
            __syncthreads();
            if (sc) s[t] += u;
            __syncthreads();
        }
        if (sc && t < nb) atomicExch(&blockoff[t], s[t] - pv);   // exclusive
        if (t == 255) rowptr[n] = s[255];                        // grand total
        __threadfence();
        if (t == 0) atomicExch(&done[1], 1);
    } else if (t == 0) {
        while (atomicAdd(&done[1], 0) == 0) __builtin_amdgcn_s_sleep(2);
        __threadfence();
    }
    __syncthreads();
    if (t == 0) boff_s = atomicAdd(&blockoff[blockIdx.x], 0);    // atomic read: coherent
    if (sc) s[t] = v;
    __syncthreads();
    for (int off = 1; off < 256; off <<= 1) {
        int u = (sc && t >= off) ? s[t - off] : 0;
        __syncthreads();
        if (sc) s[t] += u;
        __syncthreads();
    }
    if (sc && i < n) {
        rowptr[i] = boff_s + s[t] - v;
        dinv[i] = rsqrtf((float)(v + 1));
    }
    // ---- phase 2: grid-wide arrive (rowptr complete) ----
    __threadfence();
    __syncthreads();
    if (t == 0) {
        atomicAdd(&done[2], 1);
        while (atomicAdd(&done[2], 0) < nb) __builtin_amdgcn_s_sleep(2);
    }
    __syncthreads();
    // ---- phase 3: CSR fill, grid-stride ----
    int stride = nb * 1024;
    for (int e = blockIdx.x * 1024 + t; e < E; e += stride) {
        int ss = src[e], d = dst[e];
        int base = __hip_atomic_load(&rowptr[d], __ATOMIC_RELAXED,
                                     __HIP_MEMORY_SCOPE_AGENT);
        float wv = rsqrtf((float)(count[ss] + 1)) * rsqrtf((float)(count[d] + 1));
        adj[base + eslot[e]] = make_int2(ss, __float_as_int(wv));
    }
}

// ---------------- agg body for one node, F=128 (R4 readlane formulation) ----------------

__device__ __forceinline__ half2_t agg_node128(
    const half2_t* __restrict__ t2, const int* __restrict__ rowptr,
    const int2* __restrict__ adj, const float* __restrict__ dinv,
    const float* __restrict__ bias, int node, int lane) {
    float wself = dinv[node];
    wself *= wself;
    half2_t v = t2[(size_t)node * 64 + lane];
    float accx = wself * (float)v[0], accy = wself * (float)v[1];
    int beg = rowptr[node], end = rowptr[node + 1];
    for (int e0 = beg; e0 < end; e0 += 64) {
        int rem = end - e0;
        int j = 0; float w = 0.f;
        if (lane < rem) {
            int2 ed = adj[e0 + lane];
            j = ed.x; w = __int_as_float(ed.y);
        }
        int cnt = rem < 64 ? rem : 64;
        for (int c = 0; c < cnt; c += 16) {
#pragma unroll
            for (int i = 0; i < 16; i++) {
                int jj = __builtin_amdgcn_readlane(j, c + i);
                float ww = __int_as_float(
                    __builtin_amdgcn_readlane(__float_as_int(w), c + i));
                half2_t u = t2[(size_t)jj * 64 + lane];
                accx += ww * (float)u[0];
                accy += ww * (float)u[1];
            }
        }
    }
    float2 b = ((const float2*)bias)[lane];
    accx = gelu_exact(accx + b.x);
    accy = gelu_exact(accy + b.y);
    half2_t o; o[0] = (_Float16)accx; o[1] = (_Float16)accy;
    return o;
}

// ---------------- fused agg_i -> gemm_{i+1}, 16-row tiles (R3 best variant) ------------
// R4 A/B: 1-node-per-wave (46.3 us) vs this 4-node-seq (45.0 us) — gather rate is
// ~2.1 TB/s in BOTH (structural fabric/miss-queue floor, matches prev-session R6/R7
// ablations), so keep the simpler/faster 256-thread form. Fusion keeps the win of
// no hbuf round-trip (+saves a launch).

template <int BN>
__global__ __launch_bounds__(256) void agg_gemm16_kernel(
    const _Float16* __restrict__ t, const int* __restrict__ rowptr,
    const int2* __restrict__ adj, const float* __restrict__ dinv,
    const float* __restrict__ bias, const _Float16* __restrict__ Bt,
    _Float16* __restrict__ T, int M) {
    __shared__ _Float16 lds_a[16][136];
    int tid = threadIdx.x;
    int wave = tid >> 6, lane = tid & 63;
    int bm = blockIdx.x * 16;
    const half2_t* t2 = (const half2_t*)t;
#pragma unroll 1
    for (int p = 0; p < 4; p++) {
        int r = (wave << 2) + p;
        int node = bm + r;
        half2_t o;
        o[0] = (_Float16)0.f; o[1] = (_Float16)0.f;
        if (node < M) o = agg_node128(t2, rowptr, adj, dinv, bias, node, lane);
        *(half2_t*)&lds_a[r][lane << 1] = o;   // 4B/lane: conflict-free
    }
    __syncthreads();

    int m = lane & 15, quad = lane >> 4;
    const int NT = BN / 64;                    // fragments per wave: 128->2, 64->1
    float4v acc[NT];
#pragma unroll
    for (int nt = 0; nt < NT; nt++) acc[nt] = (float4v){0.f, 0.f, 0.f, 0.f};
#pragma unroll
    for (int kc = 0; kc < 128; kc += 32) {
        half8_t a = *(const half8_t*)&lds_a[m][kc + quad * 8];
#pragma unroll
        for (int nt = 0; nt < NT; nt++) {
            int col = wave * (BN / 4) + nt * 16 + m;
            half8_t b = *(const half8_t*)&Bt[(size_t)col * 128 + kc + quad * 8];
            acc[nt] = __builtin_amdgcn_mfma_f32_16x16x32_f16(a, b, acc[nt], 0, 0, 0);
        }
    }
#pragma unroll
    for (int nt = 0; nt < NT; nt++) {
#pragma unroll
        for (int r = 0; r < 4; r++) {
            int grow = bm + (quad << 2) + r;
            int col = wave * (BN / 4) + nt * 16 + m;
            if (grow < M) T[(size_t)grow * BN + col] = (_Float16)acc[nt][r];
        }
    }
}

// ---------------- final aggregation (R4 readlane formulation, R0-proven) ---------------
// out[i] = sum_e w_e*t[src_e] + dinv[i]^2*t[i] + b ; t fp16, fp32 accum, fp32 out.

template <int F, bool DOGELU, bool OUTF16>
__global__ __launch_bounds__(256) void agg_kernel(
    const _Float16* __restrict__ t, const int* __restrict__ rowptr,
    const int2* __restrict__ adj, const float* __restrict__ dinv,
    const float* __restrict__ bias, void* __restrict__ outp, int n) {
    int node = (int)((blockIdx.x * blockDim.x + threadIdx.x) >> 6);
    int lane = threadIdx.x & 63;
    if (node >= n) return;   // wave-uniform exit

    float wself = dinv[node];
    wself *= wself;
    int beg = rowptr[node];
    int end = rowptr[node + 1];

    if (F == 128) {
        const half2_t* t2 = (const half2_t*)t;
        half2_t v = t2[(size_t)node * 64 + lane];
        float accx = wself * (float)v[0], accy = wself * (float)v[1];
        for (int e0 = beg; e0 < end; e0 += 64) {
            int rem = end - e0;
            int j = 0; float w = 0.f;
            if (lane < rem) {
                int2 ed = adj[e0 + lane];
                j = ed.x; w = __int_as_float(ed.y);
            }
            int cnt = rem < 64 ? rem : 64;
            for (int c = 0; c < cnt; c += 16) {
#pragma unroll
                for (int i = 0; i < 16; i++) {
                    int jj = __builtin_amdgcn_readlane(j, c + i);
                    float ww = __int_as_float(
                        __builtin_amdgcn_readlane(__float_as_int(w), c + i));
                    half2_t u = t2[(size_t)jj * 64 + lane];
                    accx += ww * (float)u[0];
                    accy += ww * (float)u[1];
                }
            }
        }
        float2 b = ((const float2*)bias)[lane];
        accx += b.x; accy += b.y;
        if (DOGELU) { accx = gelu_exact(accx); accy = gelu_exact(accy); }
        if (OUTF16) {
            half2_t o; o[0] = (_Float16)accx; o[1] = (_Float16)accy;
            ((half2_t*)outp)[(size_t)node * 64 + lane] = o;
        } else {
            float2 o; o.x = accx; o.y = accy;
            ((float2*)outp)[(size_t)node * 64 + lane] = o;
        }
    } else {  // F == 64
        float acc = wself * (float)t[(size_t)node * 64 + lane];
        for (int e0 = beg; e0 < end; e0 += 64) {
            int rem = end - e0;
            int j = 0; float w = 0.f;
            if (lane < rem) {
                int2 ed = adj[e0 + lane];
                j = ed.x; w = __int_as_float(ed.y);
            }
            int cnt = rem < 64 ? rem : 64;
            for (int c = 0; c < cnt; c += 16) {
#pragma unroll
                for (int i = 0; i < 16; i++) {
                    int jj = __builtin_amdgcn_readlane(j, c + i);
                    float ww = __int_as_float(
                        __builtin_amdgcn_readlane(__float_as_int(w), c + i));
                    acc += ww * (float)t[(size_t)jj * 64 + lane];
                }
            }
        }
        acc += bias[lane];
        if (DOGELU) acc = gelu_exact(acc);
        if (OUTF16) ((_Float16*)outp)[(size_t)node * 64 + lane] = (_Float16)acc;
        else        ((float*)outp)[(size_t)node * 64 + lane] = acc;
    }
}

// ---------------- launch ----------------

extern "C" void kernel_launch(void* const* d_in, const int* in_sizes, int n_in,
                              void* d_out, int out_size, void* d_ws, size_t ws_size,
                              hipStream_t stream) {
    const float* x  = (const float*)d_in[0];
    const int* edge = (const int*)d_in[1];
    const float* W1 = (const float*)d_in[2];
    const float* b1 = (const float*)d_in[3];
    const float* W2 = (const float*)d_in[4];
    const float* b2 = (const float*)d_in[5];
    const float* W3 = (const float*)d_in[6];
    const float* b3 = (const float*)d_in[7];
    float* out = (float*)d_out;

    const int N = in_sizes[0] / NDIN;       // 50000
    const int E = in_sizes[1] / 2;          // 800000
    const int* src = edge;
    const int* dst = edge + E;
    const int NB = (N + 255) / 256;         // 196 (must be <= 256)

    // workspace carve-out (256B aligned)
    char* p = (char*)d_ws;
    auto alloc = [&](size_t bytes) {
        char* q = p;
        p += (bytes + 255) & ~(size_t)255;
        return q;
    };
    int*       count    = (int*)alloc((size_t)N * 4);
    int*       rowptr   = (int*)alloc((size_t)(N + 1) * 4);
    int*       blocksum = (int*)alloc((size_t)NB * 4);
    int*       blockoff = (int*)alloc((size_t)NB * 4);
    int*       done     = (int*)alloc(256);
    float*     dinv     = (float*)alloc((size_t)N * 4);
    int*       eslot    = (int*)alloc((size_t)E * 4);
    int2*      adj      = (int2*)alloc((size_t)E * 8);
    _Float16*  W1t      = (_Float16*)alloc((size_t)NHID * NDIN * 2);
    _Float16*  W2t      = (_Float16*)alloc((size_t)NHID * NHID * 2);
    _Float16*  W3t      = (_Float16*)alloc((size_t)NDOUT * NHID * 2);
    _Float16*  tbuf     = (_Float16*)alloc((size_t)N * NHID * 2);
    _Float16*  hbuf     = (_Float16*)alloc((size_t)N * NHID * 2);

    dim3 blk(256);
    dim3 blk1k(1024);
    int mtiles = (N + 63) / 64;             // 782
    int ntiles16 = (N + 15) / 16;           // 3125
    int eblocks = (E + 255) / 256;          // 3125
    int agg_blocks = (N + 3) / 4;           // 12500

    // 1. weight transpose+cast + zero count/done
    prep0_kernel<<<40 + NB, blk, 0, stream>>>(W1, W1t, W2, W2t, W3, W3t, count, done, N);
    // 2. degree count+slot || gemm1 (both depend only on prep0)
    count_gemm1_kernel<<<eblocks + mtiles, blk, 0, stream>>>(
        dst, count, eslot, E, x, W1t, tbuf, N, eblocks);
    // 3. merged scan + dinv + CSR fill (two internal device-scope syncs)
    scan_fill_kernel<<<NB, blk1k, 0, stream>>>(count, blocksum, blockoff, rowptr, dinv,
                                               done, src, dst, eslot, adj, NB, N, E);
    // 4. layer 2 fused: agg1 (gelu,b1) + gemm2 -> hbuf
    agg_gemm16_kernel<128><<<ntiles16, blk, 0, stream>>>(tbuf, rowptr, adj, dinv, b1,
                                                         W2t, hbuf, N);
    // 5. layer 3 fused: agg2 (gelu,b2) + gemm3 -> tbuf (N x 64 fp16)
    agg_gemm16_kernel<64><<<ntiles16, blk, 0, stream>>>(hbuf, rowptr, adj, dinv, b2,
                                                        W3t, tbuf, N);
    // 6. final agg (no gelu, fp32 out)
    agg_kernel<64, false, false><<<agg_blocks, blk, 0, stream>>>(tbuf, rowptr, adj,
                                                                 dinv, b3, out, N);
}

// Round 6
// 269.699 us; speedup vs baseline: 1.2327x; 1.2327x over previous
//
#include <hip/hip_runtime.h>
#include <math.h>

#define NDIN 128
#define NHID 128
#define NDOUT 64

typedef _Float16 half2_t __attribute__((ext_vector_type(2)));
typedef _Float16 half4_t __attribute__((ext_vector_type(4)));
typedef _Float16 half8_t __attribute__((ext_vector_type(8)));
typedef float    float4v __attribute__((ext_vector_type(4)));

__device__ __forceinline__ float gelu_exact(float x) {
    return 0.5f * x * (1.0f + erff(x * 0.70710678118654752f));
}

// ---------------- prep0: 3x weight transpose+cast, zero count & done ----------------
// W[K][N] fp32 -> Wt[N][K] fp16, 32x32 LDS tiles.

__device__ void wtrans_tile(const float* __restrict__ W, _Float16* __restrict__ Wt,
                            int K, int N, int bx, int by) {
    __shared__ float tile[32][33];
    int tx = threadIdx.x & 31, ty = threadIdx.x >> 5;   // ty 0..7
    for (int i = 0; i < 32; i += 8) {
        int k = by * 32 + ty + i, nn = bx * 32 + tx;
        tile[ty + i][tx] = (k < K && nn < N) ? W[(size_t)k * N + nn] : 0.f;
    }
    __syncthreads();
    for (int i = 0; i < 32; i += 8) {
        int nn = bx * 32 + ty + i, k = by * 32 + tx;
        if (nn < N && k < K) Wt[(size_t)nn * K + k] = (_Float16)tile[tx][ty + i];
    }
}

// blocks: [0,16) W1; [16,32) W2; [32,40) W3; [40,40+NB) zero count (+done in block 40)
__global__ __launch_bounds__(256) void prep0_kernel(
    const float* __restrict__ W1, _Float16* __restrict__ W1t,
    const float* __restrict__ W2, _Float16* __restrict__ W2t,
    const float* __restrict__ W3, _Float16* __restrict__ W3t,
    int* __restrict__ count, int* __restrict__ done, int n) {
    int b = blockIdx.x;
    if (b < 16) {
        wtrans_tile(W1, W1t, NDIN, NHID, b & 3, b >> 2);
    } else if (b < 32) {
        wtrans_tile(W2, W2t, NHID, NHID, (b - 16) & 3, (b - 16) >> 2);
    } else if (b < 40) {
        wtrans_tile(W3, W3t, NHID, NDOUT, (b - 32) & 1, (b - 32) >> 1);
    } else {
        int z = b - 40;
        int i = z * 256 + threadIdx.x;
        if (i < n) count[i] = 0;
        if (z == 0 && threadIdx.x < 64) done[threadIdx.x] = 0;  // done[0]=arrive, done[1]=flag
    }
}

// ---------------- shared GEMM phase: T[64,BN] tile = lds_a[64,128] @ Bt^T --------------
// B operand straight from global: 32 KB fp16 weight is L1/L2-resident after first touch.
// Only 17.4 KB LDS -> co-launched count blocks keep full occupancy.

template <int BN>
__device__ __forceinline__ void gemm_phaseB(
    const _Float16 (*lds_a)[136], const _Float16* __restrict__ Bt,
    _Float16* __restrict__ T, int bm, int M) {
    int tid = threadIdx.x;
    int wave = tid >> 6, lane = tid & 63;
    int m = lane & 15, quad = lane >> 4;
    const int NT = BN / 16;
    float4v acc[NT];
#pragma unroll
    for (int nt = 0; nt < NT; nt++) acc[nt] = (float4v){0.f, 0.f, 0.f, 0.f};
    int arow = (wave << 4) + m;
#pragma unroll
    for (int kc = 0; kc < 128; kc += 32) {
        half8_t a = *(const half8_t*)&lds_a[arow][kc + quad * 8];
#pragma unroll
        for (int nt = 0; nt < NT; nt++) {
            half8_t b = *(const half8_t*)&Bt[(size_t)(nt * 16 + m) * 128 + kc + quad * 8];
            acc[nt] = __builtin_amdgcn_mfma_f32_16x16x32_f16(a, b, acc[nt], 0, 0, 0);
        }
    }
#pragma unroll
    for (int nt = 0; nt < NT; nt++) {
#pragma unroll
        for (int r = 0; r < 4; r++) {
            int grow = bm + (wave << 4) + (quad << 2) + r;
            if (grow < M) T[(size_t)grow * BN + nt * 16 + m] = (_Float16)acc[nt][r];
        }
    }
}

// ---------------- count+slot (blocks [0,cblocks)) || gemm1 (rest) ----------------
// R4->R5 arithmetic: this fusion saved ~10 us (R5's +63.6 total = +75 scan_fill - ~10
// here). Both halves depend only on prep0. count blocks are one-atomic-each and drain
// fast, freeing CUs for the gemm blocks that follow in dispatch order.

__global__ __launch_bounds__(256) void count_gemm1_kernel(
    const int* __restrict__ dst, int* __restrict__ count, int* __restrict__ eslot, int E,
    const float* __restrict__ x, const _Float16* __restrict__ W1t,
    _Float16* __restrict__ T, int M, int cblocks) {
    __shared__ _Float16 lds_a[64][136];
    int b = blockIdx.x;
    if (b < cblocks) {                          // ---- degree count + slot assignment ----
        int e = b * 256 + threadIdx.x;
        if (e < E) eslot[e] = atomicAdd(&count[dst[e]], 1);
        return;
    }
    // ---- gemm1: stage x (fp32 -> fp16) then MFMA (global-B, 17.4 KB LDS) ----
    int bm = (b - cblocks) * 64;
    int tid = threadIdx.x;
#pragma unroll
    for (int j = 0; j < 8; j++) {
        int c = tid + j * 256;
        int r = c >> 5, col = (c & 31) << 2;
        int grow = bm + r;
        float4 v = make_float4(0.f, 0.f, 0.f, 0.f);
        if (grow < M) v = *(const float4*)(x + (size_t)grow * 128 + col);
        half4_t h;
        h[0] = (_Float16)v.x; h[1] = (_Float16)v.y;
        h[2] = (_Float16)v.z; h[3] = (_Float16)v.w;
        *(half4_t*)&lds_a[r][col] = h;
    }
    __syncthreads();
    gemm_phaseB<128>(lds_a, W1t, T, bm, M);
}

// ---------------- merged reduce + partial-scan + per-block scan + dinv ----------------
// (R3-proven form, 256 threads.) R5 lesson: do NOT bolt the TLP-hungry fill onto this
// 196-block grid — fill at 196 blocks ran at 350 GB/s (103 us). Scan stays alone.
// Last-arriving block scans the partials and raises done[1]; others spin (device-scope
// atomics only). Deadlock-free: the scanner is the last block to finish phase 1.

__global__ __launch_bounds__(256) void reduce_scan_kernel(
    const int* __restrict__ count, int* __restrict__ blocksum, int* __restrict__ blockoff,
    int* __restrict__ rowptr, float* __restrict__ dinv, int* __restrict__ done,
    int nb, int n) {
    __shared__ int s[256];
    __shared__ int flag;
    __shared__ int boff_s;
    int t = threadIdx.x;
    int i = blockIdx.x * 256 + t;
    int v = (i < n) ? count[i] : 0;
    s[t] = v;
    __syncthreads();
    for (int off = 128; off > 0; off >>= 1) {
        if (t < off) s[t] += s[t + off];
        __syncthreads();
    }
    if (t == 0) {
        atomicExch(&blocksum[blockIdx.x], s[0]);
        __threadfence();
        int old = atomicAdd(&done[0], 1);
        flag = (old == nb - 1) ? 1 : 0;
    }
    __syncthreads();
    if (flag) {  // last block: scan the per-block partials, publish offsets + flag
        __threadfence();
        int pv = (t < nb) ? atomicAdd(&blocksum[t], 0) : 0;
        s[t] = pv;
        __syncthreads();
        for (int off = 1; off < 256; off <<= 1) {
            int u = (t >= off) ? s[t - off] : 0;
            __syncthreads();
            s[t] += u;
            __syncthreads();
        }
        if (t < nb) atomicExch(&blockoff[t], s[t] - pv);   // exclusive
        if (t == 255) rowptr[n] = s[255];                  // grand total
        __threadfence();
        if (t == 0) atomicExch(&done[1], 1);
    } else if (t == 0) {
        while (atomicAdd(&done[1], 0) == 0) __builtin_amdgcn_s_sleep(2);
        __threadfence();
    }
    __syncthreads();
    if (t == 0) boff_s = atomicAdd(&blockoff[blockIdx.x], 0);  // atomic read: coherent
    s[t] = v;
    __syncthreads();
    for (int off = 1; off < 256; off <<= 1) {
        int u = (t >= off) ? s[t - off] : 0;
        __syncthreads();
        s[t] += u;
        __syncthreads();
    }
    if (i < n) {
        rowptr[i] = boff_s + s[t] - v;
        dinv[i] = rsqrtf((float)(v + 1));
    }
}

// ---------------- CSR fill (standalone, atomic-free, R3-proven: 1 edge/thread) --------

__global__ void fill_kernel(const int* __restrict__ src, const int* __restrict__ dst,
                            const int* __restrict__ eslot, const float* __restrict__ dinv,
                            const int* __restrict__ rowptr, int2* __restrict__ adj, int E) {
    int e = blockIdx.x * blockDim.x + threadIdx.x;
    if (e >= E) return;
    int s = src[e], d = dst[e];
    int p = rowptr[d] + eslot[e];
    adj[p] = make_int2(s, __float_as_int(dinv[s] * dinv[d]));
}

// ---------------- agg body for one node, F=128 (R4 readlane formulation) ----------------

__device__ __forceinline__ half2_t agg_node128(
    const half2_t* __restrict__ t2, const int* __restrict__ rowptr,
    const int2* __restrict__ adj, const float* __restrict__ dinv,
    const float* __restrict__ bias, int node, int lane) {
    float wself = dinv[node];
    wself *= wself;
    half2_t v = t2[(size_t)node * 64 + lane];
    float accx = wself * (float)v[0], accy = wself * (float)v[1];
    int beg = rowptr[node], end = rowptr[node + 1];
    for (int e0 = beg; e0 < end; e0 += 64) {
        int rem = end - e0;
        int j = 0; float w = 0.f;
        if (lane < rem) {
            int2 ed = adj[e0 + lane];
            j = ed.x; w = __int_as_float(ed.y);
        }
        int cnt = rem < 64 ? rem : 64;
        for (int c = 0; c < cnt; c += 16) {
#pragma unroll
            for (int i = 0; i < 16; i++) {
                int jj = __builtin_amdgcn_readlane(j, c + i);
                float ww = __int_as_float(
                    __builtin_amdgcn_readlane(__float_as_int(w), c + i));
                half2_t u = t2[(size_t)jj * 64 + lane];
                accx += ww * (float)u[0];
                accy += ww * (float)u[1];
            }
        }
    }
    float2 b = ((const float2*)bias)[lane];
    accx = gelu_exact(accx + b.x);
    accy = gelu_exact(accy + b.y);
    half2_t o; o[0] = (_Float16)accx; o[1] = (_Float16)accy;
    return o;
}

// ---------------- fused agg_i -> gemm_{i+1}, 16-row tiles (R3/R4 best variant) ---------
// Gather rate ~2.1 TB/s is the structural fabric/miss-queue floor (R4 A/B: 1-node/wave
// at 62% occupancy gave the same rate). Fusion keeps the no-hbuf-round-trip win.

template <int BN>
__global__ __launch_bounds__(256) void agg_gemm16_kernel(
    const _Float16* __restrict__ t, const int* __restrict__ rowptr,
    const int2* __restrict__ adj, const float* __restrict__ dinv,
    const float* __restrict__ bias, const _Float16* __restrict__ Bt,
    _Float16* __restrict__ T, int M) {
    __shared__ _Float16 lds_a[16][136];
    int tid = threadIdx.x;
    int wave = tid >> 6, lane = tid & 63;
    int bm = blockIdx.x * 16;
    const half2_t* t2 = (const half2_t*)t;
#pragma unroll 1
    for (int p = 0; p < 4; p++) {
        int r = (wave << 2) + p;
        int node = bm + r;
        half2_t o;
        o[0] = (_Float16)0.f; o[1] = (_Float16)0.f;
        if (node < M) o = agg_node128(t2, rowptr, adj, dinv, bias, node, lane);
        *(half2_t*)&lds_a[r][lane << 1] = o;   // 4B/lane: conflict-free
    }
    __syncthreads();

    int m = lane & 15, quad = lane >> 4;
    const int NT = BN / 64;                    // fragments per wave: 128->2, 64->1
    float4v acc[NT];
#pragma unroll
    for (int nt = 0; nt < NT; nt++) acc[nt] = (float4v){0.f, 0.f, 0.f, 0.f};
#pragma unroll
    for (int kc = 0; kc < 128; kc += 32) {
        half8_t a = *(const half8_t*)&lds_a[m][kc + quad * 8];
#pragma unroll
        for (int nt = 0; nt < NT; nt++) {
            int col = wave * (BN / 4) + nt * 16 + m;
            half8_t b = *(const half8_t*)&Bt[(size_t)col * 128 + kc + quad * 8];
            acc[nt] = __builtin_amdgcn_mfma_f32_16x16x32_f16(a, b, acc[nt], 0, 0, 0);
        }
    }
#pragma unroll
    for (int nt = 0; nt < NT; nt++) {
#pragma unroll
        for (int r = 0; r < 4; r++) {
            int grow = bm + (quad << 2) + r;
            int col = wave * (BN / 4) + nt * 16 + m;
            if (grow < M) T[(size_t)grow * BN + col] = (_Float16)acc[nt][r];
        }
    }
}

// ---------------- final aggregation (R4 readlane formulation, R0-proven) ---------------
// out[i] = sum_e w_e*t[src_e] + dinv[i]^2*t[i] + b ; t fp16, fp32 accum, fp32 out.

template <int F, bool DOGELU, bool OUTF16>
__global__ __launch_bounds__(256) void agg_kernel(
    const _Float16* __restrict__ t, const int* __restrict__ rowptr,
    const int2* __restrict__ adj, const float* __restrict__ dinv,
    const float* __restrict__ bias, void* __restrict__ outp, int n) {
    int node = (int)((blockIdx.x * blockDim.x + threadIdx.x) >> 6);
    int lane = threadIdx.x & 63;
    if (node >= n) return;   // wave-uniform exit

    float wself = dinv[node];
    wself *= wself;
    int beg = rowptr[node];
    int end = rowptr[node + 1];

    if (F == 128) {
        const half2_t* t2 = (const half2_t*)t;
        half2_t v = t2[(size_t)node * 64 + lane];
        float accx = wself * (float)v[0], accy = wself * (float)v[1];
        for (int e0 = beg; e0 < end; e0 += 64) {
            int rem = end - e0;
            int j = 0; float w = 0.f;
            if (lane < rem) {
                int2 ed = adj[e0 + lane];
                j = ed.x; w = __int_as_float(ed.y);
            }
            int cnt = rem < 64 ? rem : 64;
            for (int c = 0; c < cnt; c += 16) {
#pragma unroll
                for (int i = 0; i < 16; i++) {
                    int jj = __builtin_amdgcn_readlane(j, c + i);
                    float ww = __int_as_float(
                        __builtin_amdgcn_readlane(__float_as_int(w), c + i));
                    half2_t u = t2[(size_t)jj * 64 + lane];
                    accx += ww * (float)u[0];
                    accy += ww * (float)u[1];
                }
            }
        }
        float2 b = ((const float2*)bias)[lane];
        accx += b.x; accy += b.y;
        if (DOGELU) { accx = gelu_exact(accx); accy = gelu_exact(accy); }
        if (OUTF16) {
            half2_t o; o[0] = (_Float16)accx; o[1] = (_Float16)accy;
            ((half2_t*)outp)[(size_t)node * 64 + lane] = o;
        } else {
            float2 o; o.x = accx; o.y = accy;
            ((float2*)outp)[(size_t)node * 64 + lane] = o;
        }
    } else {  // F == 64
        float acc = wself * (float)t[(size_t)node * 64 + lane];
        for (int e0 = beg; e0 < end; e0 += 64) {
            int rem = end - e0;
            int j = 0; float w = 0.f;
            if (lane < rem) {
                int2 ed = adj[e0 + lane];
                j = ed.x; w = __int_as_float(ed.y);
            }
            int cnt = rem < 64 ? rem : 64;
            for (int c = 0; c < cnt; c += 16) {
#pragma unroll
                for (int i = 0; i < 16; i++) {
                    int jj = __builtin_amdgcn_readlane(j, c + i);
                    float ww = __int_as_float(
                        __builtin_amdgcn_readlane(__float_as_int(w), c + i));
                    acc += ww * (float)t[(size_t)jj * 64 + lane];
                }
            }
        }
        acc += bias[lane];
        if (DOGELU) acc = gelu_exact(acc);
        if (OUTF16) ((_Float16*)outp)[(size_t)node * 64 + lane] = (_Float16)acc;
        else        ((float*)outp)[(size_t)node * 64 + lane] = acc;
    }
}

// ---------------- launch ----------------

extern "C" void kernel_launch(void* const* d_in, const int* in_sizes, int n_in,
                              void* d_out, int out_size, void* d_ws, size_t ws_size,
                              hipStream_t stream) {
    const float* x  = (const float*)d_in[0];
    const int* edge = (const int*)d_in[1];
    const float* W1 = (const float*)d_in[2];
    const float* b1 = (const float*)d_in[3];
    const float* W2 = (const float*)d_in[4];
    const float* b2 = (const float*)d_in[5];
    const float* W3 = (const float*)d_in[6];
    const float* b3 = (const float*)d_in[7];
    float* out = (float*)d_out;

    const int N = in_sizes[0] / NDIN;       // 50000
    const int E = in_sizes[1] / 2;          // 800000
    const int* src = edge;
    const int* dst = edge + E;
    const int NB = (N + 255) / 256;         // 196 (must be <= 256)

    // workspace carve-out (256B aligned)
    char* p = (char*)d_ws;
    auto alloc = [&](size_t bytes) {
        char* q = p;
        p += (bytes + 255) & ~(size_t)255;
        return q;
    };
    int*       count    = (int*)alloc((size_t)N * 4);
    int*       rowptr   = (int*)alloc((size_t)(N + 1) * 4);
    int*       blocksum = (int*)alloc((size_t)NB * 4);
    int*       blockoff = (int*)alloc((size_t)NB * 4);
    int*       done     = (int*)alloc(256);
    float*     dinv     = (float*)alloc((size_t)N * 4);
    int*       eslot    = (int*)alloc((size_t)E * 4);
    int2*      adj      = (int2*)alloc((size_t)E * 8);
    _Float16*  W1t      = (_Float16*)alloc((size_t)NHID * NDIN * 2);
    _Float16*  W2t      = (_Float16*)alloc((size_t)NHID * NHID * 2);
    _Float16*  W3t      = (_Float16*)alloc((size_t)NDOUT * NHID * 2);
    _Float16*  tbuf     = (_Float16*)alloc((size_t)N * NHID * 2);
    _Float16*  hbuf     = (_Float16*)alloc((size_t)N * NHID * 2);

    dim3 blk(256);
    int mtiles = (N + 63) / 64;             // 782
    int ntiles16 = (N + 15) / 16;           // 3125
    int eblocks = (E + 255) / 256;          // 3125
    int agg_blocks = (N + 3) / 4;           // 12500

    // 1. weight transpose+cast + zero count/done
    prep0_kernel<<<40 + NB, blk, 0, stream>>>(W1, W1t, W2, W2t, W3, W3t, count, done, N);
    // 2. degree count+slot || gemm1 (both depend only on prep0; ~10 us win, R5 arith)
    count_gemm1_kernel<<<eblocks + mtiles, blk, 0, stream>>>(
        dst, count, eslot, E, x, W1t, tbuf, N, eblocks);
    // 3. merged reduce + scan + dinv (R3-proven, 196 x 256)
    reduce_scan_kernel<<<NB, blk, 0, stream>>>(count, blocksum, blockoff, rowptr,
                                               dinv, done, NB, N);
    // 4. CSR fill (standalone, atomic-free, 1 edge/thread — TLP-hungry, own grid)
    fill_kernel<<<eblocks, blk, 0, stream>>>(src, dst, eslot, dinv, rowptr, adj, E);
    // 5. layer 2 fused: agg1 (gelu,b1) + gemm2 -> hbuf
    agg_gemm16_kernel<128><<<ntiles16, blk, 0, stream>>>(tbuf, rowptr, adj, dinv, b1,
                                                         W2t, hbuf, N);
    // 6. layer 3 fused: agg2 (gelu,b2) + gemm3 -> tbuf (N x 64 fp16)
    agg_gemm16_kernel<64><<<ntiles16, blk, 0, stream>>>(hbuf, rowptr, adj, dinv, b2,
                                                        W3t, tbuf, N);
    // 7. final agg (no gelu, fp32 out)
    agg_kernel<64, false, false><<<agg_blocks, blk, 0, stream>>>(tbuf, rowptr, adj,
                                                                 dinv, b3, out, N);
}

// Round 7
// 268.992 us; speedup vs baseline: 1.2359x; 1.0026x over previous
//
#include <hip/hip_runtime.h>
#include <math.h>

#define NDIN 128
#define NHID 128
#define NDOUT 64
#define NREP 8   // count-replica fan-out (contention 16 -> ~2 per address)

typedef _Float16 half2_t __attribute__((ext_vector_type(2)));
typedef _Float16 half4_t __attribute__((ext_vector_type(4)));
typedef _Float16 half8_t __attribute__((ext_vector_type(8)));
typedef float    float4v __attribute__((ext_vector_type(4)));

__device__ __forceinline__ float gelu_exact(float x) {
    return 0.5f * x * (1.0f + erff(x * 0.70710678118654752f));
}

// ---------------- prep0: 3x weight transpose+cast, zero countR & done ----------------
// W[K][N] fp32 -> Wt[N][K] fp16, 32x32 LDS tiles.

__device__ void wtrans_tile(const float* __restrict__ W, _Float16* __restrict__ Wt,
                            int K, int N, int bx, int by) {
    __shared__ float tile[32][33];
    int tx = threadIdx.x & 31, ty = threadIdx.x >> 5;   // ty 0..7
    for (int i = 0; i < 32; i += 8) {
        int k = by * 32 + ty + i, nn = bx * 32 + tx;
        tile[ty + i][tx] = (k < K && nn < N) ? W[(size_t)k * N + nn] : 0.f;
    }
    __syncthreads();
    for (int i = 0; i < 32; i += 8) {
        int nn = bx * 32 + ty + i, k = by * 32 + tx;
        if (nn < N && k < K) Wt[(size_t)nn * K + k] = (_Float16)tile[tx][ty + i];
    }
}

// blocks: [0,16) W1; [16,32) W2; [32,40) W3; [40,40+NBZ) zero countR (+done in blk 40)
__global__ __launch_bounds__(256) void prep0_kernel(
    const float* __restrict__ W1, _Float16* __restrict__ W1t,
    const float* __restrict__ W2, _Float16* __restrict__ W2t,
    const float* __restrict__ W3, _Float16* __restrict__ W3t,
    int* __restrict__ countR, int* __restrict__ done, int n) {
    int b = blockIdx.x;
    if (b < 16) {
        wtrans_tile(W1, W1t, NDIN, NHID, b & 3, b >> 2);
    } else if (b < 32) {
        wtrans_tile(W2, W2t, NHID, NHID, (b - 16) & 3, (b - 16) >> 2);
    } else if (b < 40) {
        wtrans_tile(W3, W3t, NHID, NDOUT, (b - 32) & 1, (b - 32) >> 1);
    } else {
        int z = b - 40;
        int i = z * 256 + threadIdx.x;
        if (i < NREP * n) countR[i] = 0;
        if (z == 0 && threadIdx.x < 64) done[threadIdx.x] = 0;  // done[0]=arrive, done[1]=flag
    }
}

// ---------------- degree count + slot assignment, 8-way replica (R6 post-mortem fix) ---
// R6 counters: atomicAdd-WITH-RETURN to 50k addresses (16-way avg contention) was
// ~50 us hidden inside count_gemm1 (WRITE_SIZE showed ~24 MB atomic write-through).
// Return-RMWs can't merge -> serialize per address at the fabric. Replica r = blk&7
// spreads contention 16 -> ~2 and 8x the lines. r recomputable in fill: (e>>8)&7.

__global__ void count_kernel(const int* __restrict__ dst, int* __restrict__ countR,
                             int* __restrict__ eslot, int E, int n) {
    int b = blockIdx.x;
    int e = b * 256 + threadIdx.x;
    if (e < E) eslot[e] = atomicAdd(&countR[(b & (NREP - 1)) * n + dst[e]], 1);
}

// ---------------- merged reduce + partial-scan + per-block scan + dinv ----------------
// Per node: deg = sum over 8 replicas; countR converted IN PLACE to exclusive
// replica-offsets (fill adds countR[r][d]). Sync: last-arriving block scans partials
// and raises done[1]; others spin (device-scope atomics only — XCD-safe). Deadlock-free:
// the scanner is the last block to finish phase 1. nb <= 256 required (196 here).

__global__ __launch_bounds__(256) void reduce_scan_kernel(
    int* __restrict__ countR, int* __restrict__ blocksum, int* __restrict__ blockoff,
    int* __restrict__ rowptr, float* __restrict__ dinv, int* __restrict__ done,
    int nb, int n) {
    __shared__ int s[256];
    __shared__ int flag;
    __shared__ int boff_s;
    int t = threadIdx.x;
    int i = blockIdx.x * 256 + t;
    int deg = 0;
    if (i < n) {
        int pre = 0;
#pragma unroll
        for (int r = 0; r < NREP; r++) {
            int c = countR[r * n + i];     // coalesced per r
            countR[r * n + i] = pre;       // in-place exclusive replica offset
            pre += c;
        }
        deg = pre;
    }
    s[t] = deg;
    __syncthreads();
    for (int off = 128; off > 0; off >>= 1) {
        if (t < off) s[t] += s[t + off];
        __syncthreads();
    }
    if (t == 0) {
        atomicExch(&blocksum[blockIdx.x], s[0]);
        __threadfence();
        int old = atomicAdd(&done[0], 1);
        flag = (old == nb - 1) ? 1 : 0;
    }
    __syncthreads();
    if (flag) {  // last block: scan the per-block partials, publish offsets + flag
        __threadfence();
        int pv = (t < nb) ? atomicAdd(&blocksum[t], 0) : 0;
        s[t] = pv;
        __syncthreads();
        for (int off = 1; off < 256; off <<= 1) {
            int u = (t >= off) ? s[t - off] : 0;
            __syncthreads();
            s[t] += u;
            __syncthreads();
        }
        if (t < nb) atomicExch(&blockoff[t], s[t] - pv);   // exclusive
        if (t == 255) rowptr[n] = s[255];                  // grand total
        __threadfence();
        if (t == 0) atomicExch(&done[1], 1);
    } else if (t == 0) {
        while (atomicAdd(&done[1], 0) == 0) __builtin_amdgcn_s_sleep(2);
        __threadfence();
    }
    __syncthreads();
    if (t == 0) boff_s = atomicAdd(&blockoff[blockIdx.x], 0);  // atomic read: coherent
    s[t] = deg;
    __syncthreads();
    for (int off = 1; off < 256; off <<= 1) {
        int u = (t >= off) ? s[t - off] : 0;
        __syncthreads();
        s[t] += u;
        __syncthreads();
    }
    if (i < n) {
        rowptr[i] = boff_s + s[t] - deg;
        dinv[i] = rsqrtf((float)(deg + 1));
    }
}

// ---------------- CSR fill (atomic-free; slot = replica offset + local slot) ----------
// Chain: coalesced src/dst/eslot reads -> two L2-resident gathers (rowptr 200 KB,
// countR-offsets 1.6 MB) -> dinv gathers -> one scattered 8B write (write-allocate
// ~51 MB floor). blockDim MUST be 256 so (e>>8)&7 matches count_kernel's replica.

__global__ void fill_kernel(const int* __restrict__ src, const int* __restrict__ dst,
                            const int* __restrict__ eslot, const float* __restrict__ dinv,
                            const int* __restrict__ rowptr, const int* __restrict__ countR,
                            int2* __restrict__ adj, int E, int n) {
    int e = blockIdx.x * 256 + threadIdx.x;
    if (e >= E) return;
    int s = src[e], d = dst[e];
    int r = (e >> 8) & (NREP - 1);
    int p = rowptr[d] + countR[r * n + d] + eslot[e];
    adj[p] = make_int2(s, __float_as_int(dinv[s] * dinv[d]));
}

// ---------------- fp16 MFMA GEMM (R0-proven, layer 1): T = A @ Bt^T --------------------
// K fixed = 128, staged whole; 256 threads = 4 waves; wave w does rows [bm+16w,+16).

template <int BN, bool AF16>
__global__ __launch_bounds__(256) void gemm_mfma(
    const void* __restrict__ Aptr, const _Float16* __restrict__ Bt,
    _Float16* __restrict__ T, int M) {
    __shared__ _Float16 lds_a[64][136];
    __shared__ _Float16 lds_bt[BN][136];
    const int K = 128;
    int tid = threadIdx.x;
    int bm = blockIdx.x * 64;
    int wave = tid >> 6, lane = tid & 63;
    int m = lane & 15, quad = lane >> 4;

    if (AF16) {
        const _Float16* A = (const _Float16*)Aptr;
#pragma unroll
        for (int j = 0; j < 4; j++) {
            int c = tid + j * 256;
            int r = c >> 4, col = (c & 15) << 3;
            int grow = bm + r;
            uint4 v = make_uint4(0, 0, 0, 0);
            if (grow < M) v = *(const uint4*)(A + (size_t)grow * K + col);
            *(uint4*)&lds_a[r][col] = v;
        }
    } else {
        const float* A = (const float*)Aptr;
#pragma unroll
        for (int j = 0; j < 8; j++) {
            int c = tid + j * 256;
            int r = c >> 5, col = (c & 31) << 2;
            int grow = bm + r;
            float4 v = make_float4(0.f, 0.f, 0.f, 0.f);
            if (grow < M) v = *(const float4*)(A + (size_t)grow * K + col);
            half4_t h;
            h[0] = (_Float16)v.x; h[1] = (_Float16)v.y;
            h[2] = (_Float16)v.z; h[3] = (_Float16)v.w;
            *(half4_t*)&lds_a[r][col] = h;
        }
    }
    {
        const int chunks = BN * K / 8;
        for (int c = tid; c < chunks; c += 256) {
            int r = c >> 4, col = (c & 15) << 3;
            *(uint4*)&lds_bt[r][col] = *(const uint4*)(Bt + (size_t)r * K + col);
        }
    }
    __syncthreads();

    const int NT = BN / 16;
    float4v acc[NT];
#pragma unroll
    for (int nt = 0; nt < NT; nt++) acc[nt] = (float4v){0.f, 0.f, 0.f, 0.f};

    int arow = (wave << 4) + m;
#pragma unroll
    for (int kc = 0; kc < K; kc += 32) {
        half8_t a = *(const half8_t*)&lds_a[arow][kc + quad * 8];
#pragma unroll
        for (int nt = 0; nt < NT; nt++) {
            half8_t b = *(const half8_t*)&lds_bt[nt * 16 + m][kc + quad * 8];
            acc[nt] = __builtin_amdgcn_mfma_f32_16x16x32_f16(a, b, acc[nt], 0, 0, 0);
        }
    }
#pragma unroll
    for (int nt = 0; nt < NT; nt++) {
#pragma unroll
        for (int r = 0; r < 4; r++) {
            int grow = bm + (wave << 4) + (quad << 2) + r;
            if (grow < M) T[(size_t)grow * BN + nt * 16 + m] = (_Float16)acc[nt][r];
        }
    }
}

// ---------------- agg body for one node, F=128 (R4 readlane formulation) ----------------

__device__ __forceinline__ half2_t agg_node128(
    const half2_t* __restrict__ t2, const int* __restrict__ rowptr,
    const int2* __restrict__ adj, const float* __restrict__ dinv,
    const float* __restrict__ bias, int node, int lane) {
    float wself = dinv[node];
    wself *= wself;
    half2_t v = t2[(size_t)node * 64 + lane];
    float accx = wself * (float)v[0], accy = wself * (float)v[1];
    int beg = rowptr[node], end = rowptr[node + 1];
    for (int e0 = beg; e0 < end; e0 += 64) {
        int rem = end - e0;
        int j = 0; float w = 0.f;
        if (lane < rem) {
            int2 ed = adj[e0 + lane];
            j = ed.x; w = __int_as_float(ed.y);
        }
        int cnt = rem < 64 ? rem : 64;
        for (int c = 0; c < cnt; c += 16) {
#pragma unroll
            for (int i = 0; i < 16; i++) {
                int jj = __builtin_amdgcn_readlane(j, c + i);
                float ww = __int_as_float(
                    __builtin_amdgcn_readlane(__float_as_int(w), c + i));
                half2_t u = t2[(size_t)jj * 64 + lane];
                accx += ww * (float)u[0];
                accy += ww * (float)u[1];
            }
        }
    }
    float2 b = ((const float2*)bias)[lane];
    accx = gelu_exact(accx + b.x);
    accy = gelu_exact(accy + b.y);
    half2_t o; o[0] = (_Float16)accx; o[1] = (_Float16)accy;
    return o;
}

// ---------------- fused agg_i -> gemm_{i+1}, 16-row tiles (R3/R4 best variant) ---------
// Gather rate ~2.1 TB/s is the structural fabric/miss-queue floor (R4 A/B: 1-node/wave
// at 62% occupancy gave the same rate). Fusion keeps the no-hbuf-round-trip win.

template <int BN>
__global__ __launch_bounds__(256) void agg_gemm16_kernel(
    const _Float16* __restrict__ t, const int* __restrict__ rowptr,
    const int2* __restrict__ adj, const float* __restrict__ dinv,
    const float* __restrict__ bias, const _Float16* __restrict__ Bt,
    _Float16* __restrict__ T, int M) {
    __shared__ _Float16 lds_a[16][136];
    int tid = threadIdx.x;
    int wave = tid >> 6, lane = tid & 63;
    int bm = blockIdx.x * 16;
    const half2_t* t2 = (const half2_t*)t;
#pragma unroll 1
    for (int p = 0; p < 4; p++) {
        int r = (wave << 2) + p;
        int node = bm + r;
        half2_t o;
        o[0] = (_Float16)0.f; o[1] = (_Float16)0.f;
        if (node < M) o = agg_node128(t2, rowptr, adj, dinv, bias, node, lane);
        *(half2_t*)&lds_a[r][lane << 1] = o;   // 4B/lane: conflict-free
    }
    __syncthreads();

    int m = lane & 15, quad = lane >> 4;
    const int NT = BN / 64;                    // fragments per wave: 128->2, 64->1
    float4v acc[NT];
#pragma unroll
    for (int nt = 0; nt < NT; nt++) acc[nt] = (float4v){0.f, 0.f, 0.f, 0.f};
#pragma unroll
    for (int kc = 0; kc < 128; kc += 32) {
        half8_t a = *(const half8_t*)&lds_a[m][kc + quad * 8];
#pragma unroll
        for (int nt = 0; nt < NT; nt++) {
            int col = wave * (BN / 4) + nt * 16 + m;
            half8_t b = *(const half8_t*)&Bt[(size_t)col * 128 + kc + quad * 8];
            acc[nt] = __builtin_amdgcn_mfma_f32_16x16x32_f16(a, b, acc[nt], 0, 0, 0);
        }
    }
#pragma unroll
    for (int nt = 0; nt < NT; nt++) {
#pragma unroll
        for (int r = 0; r < 4; r++) {
            int grow = bm + (quad << 2) + r;
            int col = wave * (BN / 4) + nt * 16 + m;
            if (grow < M) T[(size_t)grow * BN + col] = (_Float16)acc[nt][r];
        }
    }
}

// ---------------- final aggregation (R4 readlane formulation, R0-proven) ---------------
// out[i] = sum_e w_e*t[src_e] + dinv[i]^2*t[i] + b ; t fp16, fp32 accum, fp32 out.

template <int F, bool DOGELU, bool OUTF16>
__global__ __launch_bounds__(256) void agg_kernel(
    const _Float16* __restrict__ t, const int* __restrict__ rowptr,
    const int2* __restrict__ adj, const float* __restrict__ dinv,
    const float* __restrict__ bias, void* __restrict__ outp, int n) {
    int node = (int)((blockIdx.x * blockDim.x + threadIdx.x) >> 6);
    int lane = threadIdx.x & 63;
    if (node >= n) return;   // wave-uniform exit

    float wself = dinv[node];
    wself *= wself;
    int beg = rowptr[node];
    int end = rowptr[node + 1];

    if (F == 128) {
        const half2_t* t2 = (const half2_t*)t;
        half2_t v = t2[(size_t)node * 64 + lane];
        float accx = wself * (float)v[0], accy = wself * (float)v[1];
        for (int e0 = beg; e0 < end; e0 += 64) {
            int rem = end - e0;
            int j = 0; float w = 0.f;
            if (lane < rem) {
                int2 ed = adj[e0 + lane];
                j = ed.x; w = __int_as_float(ed.y);
            }
            int cnt = rem < 64 ? rem : 64;
            for (int c = 0; c < cnt; c += 16) {
#pragma unroll
                for (int i = 0; i < 16; i++) {
                    int jj = __builtin_amdgcn_readlane(j, c + i);
                    float ww = __int_as_float(
                        __builtin_amdgcn_readlane(__float_as_int(w), c + i));
                    half2_t u = t2[(size_t)jj * 64 + lane];
                    accx += ww * (float)u[0];
                    accy += ww * (float)u[1];
                }
            }
        }
        float2 b = ((const float2*)bias)[lane];
        accx += b.x; accy += b.y;
        if (DOGELU) { accx = gelu_exact(accx); accy = gelu_exact(accy); }
        if (OUTF16) {
            half2_t o; o[0] = (_Float16)accx; o[1] = (_Float16)accy;
            ((half2_t*)outp)[(size_t)node * 64 + lane] = o;
        } else {
            float2 o; o.x = accx; o.y = accy;
            ((float2*)outp)[(size_t)node * 64 + lane] = o;
        }
    } else {  // F == 64
        float acc = wself * (float)t[(size_t)node * 64 + lane];
        for (int e0 = beg; e0 < end; e0 += 64) {
            int rem = end - e0;
            int j = 0; float w = 0.f;
            if (lane < rem) {
                int2 ed = adj[e0 + lane];
                j = ed.x; w = __int_as_float(ed.y);
            }
            int cnt = rem < 64 ? rem : 64;
            for (int c = 0; c < cnt; c += 16) {
#pragma unroll
                for (int i = 0; i < 16; i++) {
                    int jj = __builtin_amdgcn_readlane(j, c + i);
                    float ww = __int_as_float(
                        __builtin_amdgcn_readlane(__float_as_int(w), c + i));
                    acc += ww * (float)t[(size_t)jj * 64 + lane];
                }
            }
        }
        acc += bias[lane];
        if (DOGELU) acc = gelu_exact(acc);
        if (OUTF16) ((_Float16*)outp)[(size_t)node * 64 + lane] = (_Float16)acc;
        else        ((float*)outp)[(size_t)node * 64 + lane] = acc;
    }
}

// ---------------- launch ----------------

extern "C" void kernel_launch(void* const* d_in, const int* in_sizes, int n_in,
                              void* d_out, int out_size, void* d_ws, size_t ws_size,
                              hipStream_t stream) {
    const float* x  = (const float*)d_in[0];
    const int* edge = (const int*)d_in[1];
    const float* W1 = (const float*)d_in[2];
    const float* b1 = (const float*)d_in[3];
    const float* W2 = (const float*)d_in[4];
    const float* b2 = (const float*)d_in[5];
    const float* W3 = (const float*)d_in[6];
    const float* b3 = (const float*)d_in[7];
    float* out = (float*)d_out;

    const int N = in_sizes[0] / NDIN;       // 50000
    const int E = in_sizes[1] / 2;          // 800000
    const int* src = edge;
    const int* dst = edge + E;
    const int NB = (N + 255) / 256;         // 196 (must be <= 256)
    const int NBZ = (NREP * N + 255) / 256; // 1563 zero blocks

    // workspace carve-out (256B aligned)
    char* p = (char*)d_ws;
    auto alloc = [&](size_t bytes) {
        char* q = p;
        p += (bytes + 255) & ~(size_t)255;
        return q;
    };
    int*       countR   = (int*)alloc((size_t)NREP * N * 4);
    int*       rowptr   = (int*)alloc((size_t)(N + 1) * 4);
    int*       blocksum = (int*)alloc((size_t)NB * 4);
    int*       blockoff = (int*)alloc((size_t)NB * 4);
    int*       done     = (int*)alloc(256);
    float*     dinv     = (float*)alloc((size_t)N * 4);
    int*       eslot    = (int*)alloc((size_t)E * 4);
    int2*      adj      = (int2*)alloc((size_t)E * 8);
    _Float16*  W1t      = (_Float16*)alloc((size_t)NHID * NDIN * 2);
    _Float16*  W2t      = (_Float16*)alloc((size_t)NHID * NHID * 2);
    _Float16*  W3t      = (_Float16*)alloc((size_t)NDOUT * NHID * 2);
    _Float16*  tbuf     = (_Float16*)alloc((size_t)N * NHID * 2);
    _Float16*  hbuf     = (_Float16*)alloc((size_t)N * NHID * 2);

    dim3 blk(256);
    int mtiles = (N + 63) / 64;             // 782
    int ntiles16 = (N + 15) / 16;           // 3125
    int eblocks = (E + 255) / 256;          // 3125
    int agg_blocks = (N + 3) / 4;           // 12500

    // 1. weight transpose+cast + zero countR/done
    prep0_kernel<<<40 + NBZ, blk, 0, stream>>>(W1, W1t, W2, W2t, W3, W3t,
                                               countR, done, N);
    // 2. degree count + slot assignment (8-way replica atomics)
    count_kernel<<<eblocks, blk, 0, stream>>>(dst, countR, eslot, E, N);
    // 3. gemm1: x @ W1 -> tbuf (R0-proven LDS-staged GEMM)
    gemm_mfma<128, false><<<mtiles, blk, 0, stream>>>(x, W1t, tbuf, N);
    // 4. merged reduce + scan + dinv; countR -> in-place replica offsets
    reduce_scan_kernel<<<NB, blk, 0, stream>>>(countR, blocksum, blockoff, rowptr,
                                               dinv, done, NB, N);
    // 5. CSR fill (atomic-free, own 3125-block grid)
    fill_kernel<<<eblocks, blk, 0, stream>>>(src, dst, eslot, dinv, rowptr, countR,
                                             adj, E, N);
    // 6. layer 2 fused: agg1 (gelu,b1) + gemm2 -> hbuf
    agg_gemm16_kernel<128><<<ntiles16, blk, 0, stream>>>(tbuf, rowptr, adj, dinv, b1,
                                                         W2t, hbuf, N);
    // 7. layer 3 fused: agg2 (gelu,b2) + gemm3 -> tbuf (N x 64 fp16)
    agg_gemm16_kernel<64><<<ntiles16, blk, 0, stream>>>(hbuf, rowptr, adj, dinv, b2,
                                                        W3t, tbuf, N);
    // 8. final agg (no gelu, fp32 out)
    agg_kernel<64, false, false><<<agg_blocks, blk, 0, stream>>>(tbuf, rowptr, adj,
                                                                 dinv, b3, out, N);
}